// Round 3
// baseline (503.524 us; speedup 1.0000x reference)
//
#include <hip/hip_runtime.h>

// Round 10: r9 (223us rocprof) + x-part removed from LDS entirely.
// Model: step = ~2095 cyc; MFMA pipe busy only ~233 cyc (MfmaUtil ~40 is a
// FLOP-ratio, not pipe-busy), VALU reduction (r9) didn't move time -> the
// untested dominant term is the post-barrier LDS burst: 8 waves x 6 KB
// A-tile = 48 KB/step through ~85-128 B/cyc LDS = 400-576 cyc serialized.
// Fix: x never touches LDS. Each wave gathers x(t+1) fragments DIRECTLY
// from global (same pattern as the t=0 xacc init; 8 waves hit L1/L2 on the
// same 2 KB), issued a FULL STEP ahead into named even/odd float4 register
// sets (no runtime indexing). LDS A-tile = h-only (4 KB read/wave/step,
// -33%); staging writes + xf reads + pack VALU deleted. Barrier still
// lgkmcnt-only (x loads ride across it on vmcnt).
// Everything else = r9: 256x512, ROWS=8, dup-on-write M=16 h-tile, weights
// register-resident, rcp-fused elementwise, one barrier/step.

#define Bsz   2048
#define Tlen  256
#define Fdim  64
#define Hdim  128
#define ROWS  8
#define NTH   512
#define TILE_E 512            // elems per kt tile (64 lanes x 8)
#define NKT_H 4               // h-only tiles: K 0..127 of W_hh
#define BUF_E (NKT_H * TILE_E)  // 2048 bf16 = 4 KB per buffer

using bf16x8 = __attribute__((ext_vector_type(8))) __bf16;
using f32x4  = __attribute__((ext_vector_type(4))) float;

__device__ __forceinline__ float fast_rcp(float x) {
#if __has_builtin(__builtin_amdgcn_rcpf)
    return __builtin_amdgcn_rcpf(x);
#else
    return 1.0f / x;
#endif
}
__device__ __forceinline__ float fast_exp2(float x) {
#if __has_builtin(__builtin_amdgcn_exp2f)
    return __builtin_amdgcn_exp2f(x);
#else
    return exp2f(x);
#endif
}
#define LOG2E  1.4426950408889634f
#define LOG2E2 2.8853900817779268f

__device__ __forceinline__ bf16x8 cvt8(float4 a, float4 b) {
    bf16x8 r;
    r[0]=(__bf16)a.x; r[1]=(__bf16)a.y; r[2]=(__bf16)a.z; r[3]=(__bf16)a.w;
    r[4]=(__bf16)b.x; r[5]=(__bf16)b.y; r[6]=(__bf16)b.z; r[7]=(__bf16)b.w;
    return r;
}

// frag-order elem index for logical A[frag_row][k], k = H-col (h-only tile)
__device__ __forceinline__ int frag_elem(int row, int k) {
    return (k >> 5) * TILE_E + ((((k >> 3) & 3) * 16 + row) * 8) + (k & 7);
}

__global__ __launch_bounds__(NTH, 2)
void lstm_fused(const float* __restrict__ x,
                const float* __restrict__ W_ih,
                const float* __restrict__ W_hh,
                const float* __restrict__ b_ih,
                const float* __restrict__ b_hh,
                const float* __restrict__ W1,
                const float* __restrict__ b1,
                const float* __restrict__ W2,
                const float* __restrict__ b2,
                float* __restrict__ out)
{
    __shared__ __bf16 Abuf[2][BUF_E];       // 8 KB total, h fragments only
    __shared__ float  hlast[ROWS * Hdim];   // 4 KB fp32 h_T for head
    __shared__ float  zbuf[ROWS * 32];

    const int tid  = threadIdx.x;
    const int w    = tid >> 6;
    const int lane = tid & 63;
    const int quad = lane >> 4;
    const int l16  = lane & 15;
    const int b0   = blockIdx.x * ROWS;
    const bool hiq = (quad >= 2);           // selects acc elems {2,3} vs {0,1}

    // ---- weights, register-resident: x-part (2 kt) + h-part (4 kt) ----
    // lane holds B[k = kt*32 + quad*8 + j][n = g*128 + w*16 + l16]
    bf16x8 bwx[2][4], bwh[4][4];
    #pragma unroll
    for (int kt = 0; kt < 6; ++kt) {
        const int k0 = kt * 32 + quad * 8;
        #pragma unroll
        for (int g = 0; g < 4; ++g) {
            const int n = g * Hdim + w * 16 + l16;
            const float* p = (kt < 2) ? (W_ih + (size_t)n * Fdim + k0)
                                      : (W_hh + (size_t)n * Hdim + (k0 - Fdim));
            float4 lo = *(const float4*)p;
            float4 hi = *(const float4*)(p + 4);
            bf16x8 r = cvt8(lo, hi);
            if (kt < 2) bwx[kt][g] = r; else bwh[kt - 2][g] = r;
        }
    }
    // bias pre-splatted into f32x4 regs; used directly as MFMA C-in
    f32x4 biasf[4];
    #pragma unroll
    for (int g = 0; g < 4; ++g) {
        const int n = g * Hdim + w * 16 + l16;
        const float bv = b_ih[n] + b_hh[n];
        biasf[g] = (f32x4){bv, bv, bv, bv};
    }

    // ---- x fragment gather base (per-lane, dup rows via l16&7) ----
    // A[row=l16][k=quad*8+j (kt0) / 32+quad*8+j (kt1)] for timestep tt is at
    // xq + tt*Fdim + {0..3, 4..7} and + {32..35, 36..39}.
    const float* xq = x + (size_t)(b0 + (l16 & 7)) * (Tlen * Fdim) + quad * 8;

    // ---- elementwise cells (r5 mapping): 2 real cells/lane ----
    const int r0  = (quad >> 1) * 2;
    const int brb = (quad & 1) * 4 + r0;     // batch rows brb, brb+1
    const int hc  = 16 * w + l16;            // H-col 0..127
    const int h_e0a = frag_elem(brb,         hc);
    const int h_e0b = frag_elem(brb + 8,     hc);
    const int h_e1a = frag_elem(brb + 1,     hc);
    const int h_e1b = frag_elem(brb + 1 + 8, hc);

    // ---- init: zero buf0 (h0 = 0) ----
    #pragma unroll
    for (int i = 0; i < BUF_E / NTH; ++i)
        Abuf[0][tid + i * NTH] = (__bf16)0.0f;

    // prologue: x(1) fragments -> register set A (consumed end of step 0)
    float4 xA0, xA1, xA2, xA3, xB0, xB1, xB2, xB3;
    xB0 = xB1 = xB2 = xB3 = make_float4(0.f, 0.f, 0.f, 0.f);
    {
        const float* p = xq + (size_t)1 * Fdim;
        xA0 = *(const float4*)(p);
        xA1 = *(const float4*)(p + 4);
        xA2 = *(const float4*)(p + 32);
        xA3 = *(const float4*)(p + 36);
    }
    // xacc(0) = bias + x(0) W_ih^T from direct global fragment loads
    f32x4 xacc[4];
    {
        float4 a0 = *(const float4*)(xq);
        float4 a1 = *(const float4*)(xq + 4);
        float4 a2 = *(const float4*)(xq + 32);
        float4 a3 = *(const float4*)(xq + 36);
        bf16x8 xi0 = cvt8(a0, a1), xi1 = cvt8(a2, a3);
        #pragma unroll
        for (int g = 0; g < 4; ++g) {
            f32x4 tmp = __builtin_amdgcn_mfma_f32_16x16x32_bf16(xi0, bwx[0][g], biasf[g], 0, 0, 0);
            xacc[g]   = __builtin_amdgcn_mfma_f32_16x16x32_bf16(xi1, bwx[1][g], tmp, 0, 0, 0);
        }
    }
    __syncthreads();

    float cc0 = 0.0f, cc1 = 0.0f;

    // One step. Program order: [4x ds_read_b128 (h) | issue x(t+2) global
    // loads | 16 h-MFMA | cvt+8 x-MFMA (x(t+1), loaded LAST step: zero
    // stall) | sched_barrier | elementwise | h-writes | lgkmcnt | s_barrier].
    // xh* = x(t+1) frags (consume), xl* = x(t+2) frags (load target).
    auto step = [&](int t, const __bf16* __restrict__ rb,
                    __bf16* __restrict__ wbf,
                    float4& xh0, float4& xh1, float4& xh2, float4& xh3,
                    float4& xl0, float4& xl1, float4& xl2, float4& xl3) {
        // h(t-1) fragments: 4x conflict-free ds_read_b128 at lane*16B
        bf16x8 hf[4];
        #pragma unroll
        for (int kt = 0; kt < NKT_H; ++kt)
            hf[kt] = *(const bf16x8*)&rb[kt * TILE_E + lane * 8];

        // issue x(t+2) fragment loads (L1/L2-served; consumed NEXT step;
        // ride across the barrier on vmcnt -- never drained in-loop)
        if ((t + 2) < Tlen) {
            const float* p = xq + (size_t)(t + 2) * Fdim;
            xl0 = *(const float4*)(p);
            xl1 = *(const float4*)(p + 4);
            xl2 = *(const float4*)(p + 32);
            xl3 = *(const float4*)(p + 36);
        }

        // gates(t) = xacc(t) + h-part: 16 MFMAs; xacc folded in as C operand
        f32x4 acc[4];
        #pragma unroll
        for (int g = 0; g < 4; ++g)
            acc[g] = __builtin_amdgcn_mfma_f32_16x16x32_bf16(hf[0], bwh[0][g], xacc[g], 0, 0, 0);
        #pragma unroll
        for (int kt = 1; kt < NKT_H; ++kt) {
            #pragma unroll
            for (int g = 0; g < 4; ++g)
                acc[g] = __builtin_amdgcn_mfma_f32_16x16x32_bf16(hf[kt], bwh[kt][g], acc[g], 0, 0, 0);
        }

        // xacc(t+1) = bias + x(t+1) W_ih^T -- x frags loaded a full step
        // ago, so no vmcnt stall; MFMA pipe drains these under elementwise.
        if ((t + 1) < Tlen) {
            bf16x8 xi0 = cvt8(xh0, xh1), xi1 = cvt8(xh2, xh3);
            #pragma unroll
            for (int g = 0; g < 4; ++g) {
                f32x4 tmp = __builtin_amdgcn_mfma_f32_16x16x32_bf16(xi0, bwx[0][g], biasf[g], 0, 0, 0);
                xacc[g]   = __builtin_amdgcn_mfma_f32_16x16x32_bf16(xi1, bwx[1][g], tmp, 0, 0, 0);
            }
        }

        // pin: all memory issue + MFMA issue above the elementwise phase
        __builtin_amdgcn_sched_barrier(0);

        // elementwise: 2 cells/lane, rcp-fused gate math.
        {
            float gi = hiq ? acc[0][2] : acc[0][0];
            float gf = hiq ? acc[1][2] : acc[1][0];
            float gg = hiq ? acc[2][2] : acc[2][0];
            float go = hiq ? acc[3][2] : acc[3][0];
            float ei = fast_exp2(-LOG2E  * gi);
            float ef = fast_exp2(-LOG2E  * gf);
            float eg = fast_exp2(-LOG2E2 * gg);
            float eo = fast_exp2(-LOG2E  * go);
            float a = 1.0f + ef, b = 1.0f + ei, d = 1.0f + eg;
            float bd  = b * d;
            float num = cc0 * bd + a * (1.0f - eg);
            cc0 = num * fast_rcp(a * bd);
            float ec = fast_exp2(-LOG2E2 * cc0);
            float h  = (1.0f - ec) * fast_rcp((1.0f + eo) * (1.0f + ec));
            __bf16 hb = (__bf16)h;
            wbf[h_e0a] = hb;
            wbf[h_e0b] = hb;
            if (t == Tlen - 1) hlast[brb * Hdim + hc] = h;
        }
        {
            float gi = hiq ? acc[0][3] : acc[0][1];
            float gf = hiq ? acc[1][3] : acc[1][1];
            float gg = hiq ? acc[2][3] : acc[2][1];
            float go = hiq ? acc[3][3] : acc[3][1];
            float ei = fast_exp2(-LOG2E  * gi);
            float ef = fast_exp2(-LOG2E  * gf);
            float eg = fast_exp2(-LOG2E2 * gg);
            float eo = fast_exp2(-LOG2E  * go);
            float a = 1.0f + ef, b = 1.0f + ei, d = 1.0f + eg;
            float bd  = b * d;
            float num = cc1 * bd + a * (1.0f - eg);
            cc1 = num * fast_rcp(a * bd);
            float ec = fast_exp2(-LOG2E2 * cc1);
            float h  = (1.0f - ec) * fast_rcp((1.0f + eo) * (1.0f + ec));
            __bf16 hb = (__bf16)h;
            wbf[h_e1a] = hb;
            wbf[h_e1b] = hb;
            if (t == Tlen - 1) hlast[(brb + 1) * Hdim + hc] = h;
        }

        // non-draining barrier: LDS visible (lgkmcnt 0); x loads stay in
        // flight (NO vmcnt drain).
        asm volatile("s_waitcnt lgkmcnt(0)" ::: "memory");
        __builtin_amdgcn_s_barrier();
        __builtin_amdgcn_sched_barrier(0);
    };

    for (int t = 0; t < Tlen; t += 2) {
        step(t,     Abuf[0], Abuf[1], xA0, xA1, xA2, xA3, xB0, xB1, xB2, xB3);
        step(t + 1, Abuf[1], Abuf[0], xB0, xB1, xB2, xB3, xA0, xA1, xA2, xA3);
    }

    // ---- head: z = relu(h @ W1^T + b1); out = sigmoid(z @ W2^T + b2) ----
    // (final loop barrier drained lgkmcnt and synced all waves: hlast safe)
    if (tid < ROWS * 32) {
        const int b = tid >> 5, n = tid & 31;
        const float4* w4 = (const float4*)(W1 + n * Hdim);
        const float4* h4 = (const float4*)(hlast + b * Hdim);
        float s = b1[n];
        #pragma unroll
        for (int kk = 0; kk < Hdim / 4; ++kk) {
            float4 wv = w4[kk];
            float4 hv = h4[kk];
            s += wv.x * hv.x + wv.y * hv.y + wv.z * hv.z + wv.w * hv.w;
        }
        zbuf[b * 32 + n] = fmaxf(s, 0.0f);
    }
    __syncthreads();
    if (tid < ROWS) {
        float s = b2[0];
        #pragma unroll
        for (int n = 0; n < 32; ++n) s += zbuf[tid * 32 + n] * W2[n];
        float e = fast_exp2(-LOG2E * s);
        out[b0 + tid] = fast_rcp(1.0f + e);
    }
}

extern "C" void kernel_launch(void* const* d_in, const int* in_sizes, int n_in,
                              void* d_out, int out_size, void* d_ws, size_t ws_size,
                              hipStream_t stream) {
    const float* x    = (const float*)d_in[0];
    const float* W_ih = (const float*)d_in[1];
    const float* W_hh = (const float*)d_in[2];
    const float* b_ih = (const float*)d_in[3];
    const float* b_hh = (const float*)d_in[4];
    const float* W1   = (const float*)d_in[5];
    const float* b1   = (const float*)d_in[6];
    const float* W2   = (const float*)d_in[7];
    const float* b2   = (const float*)d_in[8];
    float* out = (float*)d_out;

    dim3 grid(Bsz / ROWS), block(NTH);
    lstm_fused<<<grid, block, 0, stream>>>(x, W_ih, W_hh, b_ih, b_hh, W1, b1, W2, b2, out);
}

// Round 4
// 366.335 us; speedup vs baseline: 1.3745x; 1.3745x over previous
//
#include <hip/hip_runtime.h>

// Round 11: r9 revert (223us proven) + x-GEMM 2-step packing + prescale.
// r10 lesson: per-step per-lane global gathers = cold scattered HBM reads,
// +70%. Keep r9's coalesced LDS staging.
// New in r11:
//  (H) The M=16 dup rows become useful: A-tile x-slots hold rows 0-7 =
//      x(t+1), rows 8-15 = x(t+2) (same batch rows). ONE 8-MFMA x-GEMM per
//      TWO steps (odd steps) produces P = bias + x*W_ih^T for both steps.
//      Row-half redistribution via ds_bpermute(lane^32) + hiq selects ->
//      xE/xO used as h-GEMM C-in. x-MFMA work halves: -155 cyc/SIMD/step.
//  (E) Weights/bias prescaled by -log2e (i,f,o) and -2log2e (g): the
//      elementwise exp2 consumes acc directly (drops 4 muls/cell).
//  (S) Staging spread over all 512 threads (1 write each, every other
//      step): balances barrier arrival, halves staging writes.
// Kept: 256x512, ROWS=8, frag-order A-tile, weights in 96 VGPRs,
// rcp-fused elementwise, non-draining (lgkmcnt-only) barrier, 2-step
// coalesced x prefetch into registers.

#define Bsz   2048
#define Tlen  256
#define Fdim  64
#define Hdim  128
#define ROWS  8
#define NTH   512
#define TILE_E 512            // elems per kt tile (64 lanes x 8)
#define NKT   6               // kt 0,1 = x slots; kt 2..5 = h (K 64..191)
#define BUF_E (NKT * TILE_E)  // 3072 bf16 = 6 KB per buffer

using bf16x8 = __attribute__((ext_vector_type(8))) __bf16;
using f32x4  = __attribute__((ext_vector_type(4))) float;

__device__ __forceinline__ float fast_rcp(float x) {
#if __has_builtin(__builtin_amdgcn_rcpf)
    return __builtin_amdgcn_rcpf(x);
#else
    return 1.0f / x;
#endif
}
__device__ __forceinline__ float fast_exp2(float x) {
#if __has_builtin(__builtin_amdgcn_exp2f)
    return __builtin_amdgcn_exp2f(x);
#else
    return exp2f(x);
#endif
}
#define LOG2E  1.4426950408889634f
#define LOG2E2 2.8853900817779268f

__device__ __forceinline__ bf16x8 cvt8(float4 a, float4 b) {
    bf16x8 r;
    r[0]=(__bf16)a.x; r[1]=(__bf16)a.y; r[2]=(__bf16)a.z; r[3]=(__bf16)a.w;
    r[4]=(__bf16)b.x; r[5]=(__bf16)b.y; r[6]=(__bf16)b.z; r[7]=(__bf16)b.w;
    return r;
}
__device__ __forceinline__ bf16x8 cvt8s(float4 a, float4 b, float s) {
    bf16x8 r;
    r[0]=(__bf16)(s*a.x); r[1]=(__bf16)(s*a.y); r[2]=(__bf16)(s*a.z); r[3]=(__bf16)(s*a.w);
    r[4]=(__bf16)(s*b.x); r[5]=(__bf16)(s*b.y); r[6]=(__bf16)(s*b.z); r[7]=(__bf16)(s*b.w);
    return r;
}

// frag-order elem index for logical A[frag_row][k]
__device__ __forceinline__ int frag_elem(int row, int k) {
    return (k >> 5) * TILE_E + ((((k >> 3) & 3) * 16 + row) * 8) + (k & 7);
}

__global__ __launch_bounds__(NTH, 2)
void lstm_fused(const float* __restrict__ x,
                const float* __restrict__ W_ih,
                const float* __restrict__ W_hh,
                const float* __restrict__ b_ih,
                const float* __restrict__ b_hh,
                const float* __restrict__ W1,
                const float* __restrict__ b1,
                const float* __restrict__ W2,
                const float* __restrict__ b2,
                float* __restrict__ out)
{
    __shared__ __bf16 Abuf[2][BUF_E];       // 12 KB, fragment-order A operand
    __shared__ float  hlast[ROWS * Hdim];   // 4 KB fp32 h_T for head
    __shared__ float  zbuf[ROWS * 32];

    const int tid  = threadIdx.x;
    const int w    = tid >> 6;
    const int lane = tid & 63;
    const int quad = lane >> 4;
    const int l16  = lane & 15;
    const int b0   = blockIdx.x * ROWS;
    const bool hiq = (quad >= 2);           // acc/P elems {2,3} vs {0,1}
    const int bpaddr = (lane ^ 32) << 2;    // ds_bpermute half-swap index

    // ---- weights, register-resident, PRESCALED by gate nonlinearity ----
    // scale: i,f,o -> -log2e ; g -> -2*log2e  (exp2(acc) = exp(-z)/exp(-2z))
    bf16x8 bwx[2][4], bwh[4][4];
    #pragma unroll
    for (int kt = 0; kt < NKT; ++kt) {
        const int k0 = kt * 32 + quad * 8;
        #pragma unroll
        for (int g = 0; g < 4; ++g) {
            const float s = (g == 2) ? -LOG2E2 : -LOG2E;
            const int n = g * Hdim + w * 16 + l16;
            const float* p = (kt < 2) ? (W_ih + (size_t)n * Fdim + k0)
                                      : (W_hh + (size_t)n * Hdim + (k0 - Fdim));
            float4 lo = *(const float4*)p;
            float4 hi = *(const float4*)(p + 4);
            bf16x8 r = cvt8s(lo, hi, s);
            if (kt < 2) bwx[kt][g] = r; else bwh[kt - 2][g] = r;
        }
    }
    f32x4 biasf[4];
    #pragma unroll
    for (int g = 0; g < 4; ++g) {
        const float s = (g == 2) ? -LOG2E2 : -LOG2E;
        const int n = g * Hdim + w * 16 + l16;
        const float bv = s * (b_ih[n] + b_hh[n]);
        biasf[g] = (f32x4){bv, bv, bv, bv};
    }

    // ---- x staging: ALL 512 threads, one uint write per 2 steps ----
    // thread -> (row = tid&7, feat pair fp, half): half 0 writes rows 0-7
    // slot (= x(t+2)), half 1 writes rows 8-15 slot (= x(t+3)).
    const int  sx_row  = tid & 7;
    const int  sx_fp   = (tid >> 3) & 31;
    const int  sx_half = (tid >> 8) & 1;
    const int  f0      = 2 * sx_fp;
    const float* xrp   = x + (size_t)(b0 + sx_row) * (Tlen * Fdim) + f0;
    const int  sx_e    = frag_elem(sx_row + 8 * sx_half, f0);

    // ---- elementwise cells (r5 mapping): 2 real cells/lane ----
    const int r0  = (quad >> 1) * 2;
    const int brb = (quad & 1) * 4 + r0;     // batch rows brb, brb+1
    const int hc  = 16 * w + l16;            // H-col 0..127
    const int h_e0a = frag_elem(brb,         Fdim + hc);
    const int h_e0b = frag_elem(brb + 8,     Fdim + hc);
    const int h_e1a = frag_elem(brb + 1,     Fdim + hc);
    const int h_e1b = frag_elem(brb + 1 + 8, Fdim + hc);

    // ---- init: zero buf0 (h0 = 0); prologue staging register ----
    #pragma unroll
    for (int i = 0; i < BUF_E / NTH; ++i)
        Abuf[0][tid + i * NTH] = (__bf16)0.0f;
    // staged value for step-0 staging: x(2+half) feature pair
    float2 xpv = *(const float2*)(xrp + (size_t)(2 + sx_half) * Fdim);

    // xE = C-in for even steps, xO = C-in for odd steps (bias + x W_ih^T,
    // prescaled). Built from P (packed 2-step x-GEMM) via half-swap.
    f32x4 xE[4], xO[4];
    {
        // prologue P: rows 0-7 = x(0), rows 8-15 = x(1), direct global
        // gather: lane row = l16 -> batch (l16&7), timestep (l16>>3).
        const float* xg = x + (size_t)(b0 + (l16 & 7)) * (Tlen * Fdim)
                            + (size_t)(l16 >> 3) * Fdim + quad * 8;
        float4 a0 = *(const float4*)(xg);
        float4 a1 = *(const float4*)(xg + 4);
        float4 a2 = *(const float4*)(xg + 32);
        float4 a3 = *(const float4*)(xg + 36);
        bf16x8 xi0 = cvt8(a0, a1), xi1 = cvt8(a2, a3);
        #pragma unroll
        for (int g = 0; g < 4; ++g) {
            f32x4 tmp = __builtin_amdgcn_mfma_f32_16x16x32_bf16(xi0, bwx[0][g], biasf[g], 0, 0, 0);
            f32x4 P   = __builtin_amdgcn_mfma_f32_16x16x32_bf16(xi1, bwx[1][g], tmp, 0, 0, 0);
            #pragma unroll
            for (int e = 0; e < 4; ++e) {
                float sv = __int_as_float(
                    __builtin_amdgcn_ds_bpermute(bpaddr, __float_as_int(P[e])));
                xE[g][e] = hiq ? sv   : P[e];
                xO[g][e] = hiq ? P[e] : sv;
            }
        }
    }
    __syncthreads();

    float cc0 = 0.0f, cc1 = 0.0f;

    // shared elementwise: 2 cells/lane, rcp-fused, prescaled gates.
    auto cellmath = [&](int t, f32x4* acc, __bf16* __restrict__ wbf) {
        {
            float ei = fast_exp2(hiq ? acc[0][2] : acc[0][0]);
            float ef = fast_exp2(hiq ? acc[1][2] : acc[1][0]);
            float eg = fast_exp2(hiq ? acc[2][2] : acc[2][0]);
            float eo = fast_exp2(hiq ? acc[3][2] : acc[3][0]);
            float a = 1.0f + ef, b = 1.0f + ei, d = 1.0f + eg;
            float bd  = b * d;
            float num = cc0 * bd + a * (1.0f - eg);
            cc0 = num * fast_rcp(a * bd);
            float ec = fast_exp2(-LOG2E2 * cc0);
            float h  = (1.0f - ec) * fast_rcp((1.0f + eo) * (1.0f + ec));
            __bf16 hb = (__bf16)h;
            wbf[h_e0a] = hb;
            wbf[h_e0b] = hb;
            if (t == Tlen - 1) hlast[brb * Hdim + hc] = h;
        }
        {
            float ei = fast_exp2(hiq ? acc[0][3] : acc[0][1]);
            float ef = fast_exp2(hiq ? acc[1][3] : acc[1][1]);
            float eg = fast_exp2(hiq ? acc[2][3] : acc[2][1]);
            float eo = fast_exp2(hiq ? acc[3][3] : acc[3][1]);
            float a = 1.0f + ef, b = 1.0f + ei, d = 1.0f + eg;
            float bd  = b * d;
            float num = cc1 * bd + a * (1.0f - eg);
            cc1 = num * fast_rcp(a * bd);
            float ec = fast_exp2(-LOG2E2 * cc1);
            float h  = (1.0f - ec) * fast_rcp((1.0f + eo) * (1.0f + ec));
            __bf16 hb = (__bf16)h;
            wbf[h_e1a] = hb;
            wbf[h_e1b] = hb;
            if (t == Tlen - 1) hlast[(brb + 1) * Hdim + hc] = h;
        }
    };

    // EVEN step t: h-MFMAs (C-in = xE) + staging write/load; no x-GEMM.
    auto stepE = [&](int t, const __bf16* __restrict__ rb,
                     __bf16* __restrict__ wbf) {
        bf16x8 hf[4];
        #pragma unroll
        for (int kt = 0; kt < 4; ++kt)
            hf[kt] = *(const bf16x8*)&rb[(2 + kt) * TILE_E + lane * 8];

        // stage x(t+2)/x(t+3) (held in xpv) into wbf x-slots, one write/thread
        if ((t + 2) < Tlen) {
            __bf16 xa[2] = {(__bf16)xpv.x, (__bf16)xpv.y};
            *(uint*)&wbf[sx_e] = *(uint*)xa;
        }
        // issue coalesced load for x(t+4)/x(t+5): 2 full steps of slack,
        // rides across barriers on vmcnt (never drained in-loop)
        if ((t + 4) < Tlen)
            xpv = *(const float2*)(xrp + (size_t)(t + 4 + sx_half) * Fdim);

        f32x4 acc[4];
        #pragma unroll
        for (int g = 0; g < 4; ++g)
            acc[g] = __builtin_amdgcn_mfma_f32_16x16x32_bf16(hf[0], bwh[0][g], xE[g], 0, 0, 0);
        #pragma unroll
        for (int kt = 1; kt < 4; ++kt) {
            #pragma unroll
            for (int g = 0; g < 4; ++g)
                acc[g] = __builtin_amdgcn_mfma_f32_16x16x32_bf16(hf[kt], bwh[kt][g], acc[g], 0, 0, 0);
        }

        __builtin_amdgcn_sched_barrier(0);
        cellmath(t, acc, wbf);

        asm volatile("s_waitcnt lgkmcnt(0)" ::: "memory");
        __builtin_amdgcn_s_barrier();
        __builtin_amdgcn_sched_barrier(0);
    };

    // ODD step t: h-MFMAs (C-in = xO) + packed x-GEMM for steps t+1, t+2.
    auto stepO = [&](int t, const __bf16* __restrict__ rb,
                     __bf16* __restrict__ wbf) {
        bf16x8 hf[4];
        #pragma unroll
        for (int kt = 0; kt < 4; ++kt)
            hf[kt] = *(const bf16x8*)&rb[(2 + kt) * TILE_E + lane * 8];
        // x frags: rows 0-7 = x(t+1), rows 8-15 = x(t+2) (staged last step)
        bf16x8 xf0 = *(const bf16x8*)&rb[lane * 8];
        bf16x8 xf1 = *(const bf16x8*)&rb[TILE_E + lane * 8];

        f32x4 acc[4];
        #pragma unroll
        for (int g = 0; g < 4; ++g)
            acc[g] = __builtin_amdgcn_mfma_f32_16x16x32_bf16(hf[0], bwh[0][g], xO[g], 0, 0, 0);
        #pragma unroll
        for (int kt = 1; kt < 4; ++kt) {
            #pragma unroll
            for (int g = 0; g < 4; ++g)
                acc[g] = __builtin_amdgcn_mfma_f32_16x16x32_bf16(hf[kt], bwh[kt][g], acc[g], 0, 0, 0);
        }

        // packed x-GEMM: P rows 0-7 -> xpart(t+1), rows 8-15 -> xpart(t+2);
        // half-swap (ds_bpermute lane^32) + hiq selects build next xE/xO.
        // Issued before elementwise: MFMA pipe drains it under the VALU.
        if ((t + 1) < Tlen) {
            #pragma unroll
            for (int g = 0; g < 4; ++g) {
                f32x4 tmp = __builtin_amdgcn_mfma_f32_16x16x32_bf16(xf0, bwx[0][g], biasf[g], 0, 0, 0);
                f32x4 P   = __builtin_amdgcn_mfma_f32_16x16x32_bf16(xf1, bwx[1][g], tmp, 0, 0, 0);
                #pragma unroll
                for (int e = 0; e < 4; ++e) {
                    float sv = __int_as_float(
                        __builtin_amdgcn_ds_bpermute(bpaddr, __float_as_int(P[e])));
                    xE[g][e] = hiq ? sv   : P[e];
                    xO[g][e] = hiq ? P[e] : sv;
                }
            }
        }

        __builtin_amdgcn_sched_barrier(0);
        cellmath(t, acc, wbf);

        asm volatile("s_waitcnt lgkmcnt(0)" ::: "memory");
        __builtin_amdgcn_s_barrier();
        __builtin_amdgcn_sched_barrier(0);
    };

    for (int t = 0; t < Tlen; t += 2) {
        stepE(t,     Abuf[0], Abuf[1]);
        stepO(t + 1, Abuf[1], Abuf[0]);
    }

    // ---- head: z = relu(h @ W1^T + b1); out = sigmoid(z @ W2^T + b2) ----
    // (final loop barrier drained lgkmcnt and synced all waves: hlast safe)
    if (tid < ROWS * 32) {
        const int b = tid >> 5, n = tid & 31;
        const float4* w4 = (const float4*)(W1 + n * Hdim);
        const float4* h4 = (const float4*)(hlast + b * Hdim);
        float s = b1[n];
        #pragma unroll
        for (int kk = 0; kk < Hdim / 4; ++kk) {
            float4 wv = w4[kk];
            float4 hv = h4[kk];
            s += wv.x * hv.x + wv.y * hv.y + wv.z * hv.z + wv.w * hv.w;
        }
        zbuf[b * 32 + n] = fmaxf(s, 0.0f);
    }
    __syncthreads();
    if (tid < ROWS) {
        float s = b2[0];
        #pragma unroll
        for (int n = 0; n < 32; ++n) s += zbuf[tid * 32 + n] * W2[n];
        float e = fast_exp2(-LOG2E * s);
        out[b0 + tid] = fast_rcp(1.0f + e);
    }
}

extern "C" void kernel_launch(void* const* d_in, const int* in_sizes, int n_in,
                              void* d_out, int out_size, void* d_ws, size_t ws_size,
                              hipStream_t stream) {
    const float* x    = (const float*)d_in[0];
    const float* W_ih = (const float*)d_in[1];
    const float* W_hh = (const float*)d_in[2];
    const float* b_ih = (const float*)d_in[3];
    const float* b_hh = (const float*)d_in[4];
    const float* W1   = (const float*)d_in[5];
    const float* b1   = (const float*)d_in[6];
    const float* W2   = (const float*)d_in[7];
    const float* b2   = (const float*)d_in[8];
    float* out = (float*)d_out;

    dim3 grid(Bsz / ROWS), block(NTH);
    lstm_fused<<<grid, block, 0, stream>>>(x, W_ih, W_hh, b_ih, b_hh, W1, b1, W2, b2, out);
}